// Round 1
// baseline (5407.511 us; speedup 1.0000x reference)
//
#include <hip/hip_runtime.h>
#include <hip/hip_bf16.h>

typedef __bf16 bf16x8 __attribute__((ext_vector_type(8)));
typedef float f32x4 __attribute__((ext_vector_type(4)));
typedef unsigned short ushort8 __attribute__((ext_vector_type(8)));
typedef float float4v __attribute__((ext_vector_type(4)));

#define DEVI __device__ __forceinline__

// ---- sizes (compile-time) ----
#define NSEQ 256      // A_*BS
#define TT 256        // T
#define VV 128        // V
#define EE 512        // E
#define HH 512        // H
#define NA 64
#define MROWS 65536   // NSEQ*T
#define G3 1536       // 3*H

DEVI unsigned short f2bf(float f) {
  union { float f; unsigned u; } v; v.f = f;
  unsigned r = v.u + 0x7fffu + ((v.u >> 16) & 1u);
  return (unsigned short)(r >> 16);
}
DEVI float bf2f(unsigned short s) {
  union { unsigned u; float f; } v; v.u = ((unsigned)s) << 16;
  return v.f;
}
DEVI bf16x8 ld_bf8_g(const unsigned short* p) {        // 16B-aligned global/LDS load
  ushort8 v = *(const ushort8*)p;
  return __builtin_bit_cast(bf16x8, v);
}
DEVI bf16x8 ld_bf8_b(const char* base, unsigned byte) { // byte-addressed (swizzled LDS)
  ushort8 v = *(const ushort8*)(base + byte);
  return __builtin_bit_cast(bf16x8, v);
}
DEVI void gload_lds16(const void* g, unsigned short* lds_base, unsigned lds_byte_off) {
  __builtin_amdgcn_global_load_lds(
      (const __attribute__((address_space(1))) unsigned int*)g,
      (__attribute__((address_space(3))) unsigned int*)(void*)((char*)lds_base + lds_byte_off),
      16, 0, 0);
}

// ---------- cast fp32 -> bf16(raw u16) ----------
__global__ void cast_f32_bf16(const float* __restrict__ src, unsigned short* __restrict__ dst, int n) {
  int i = blockIdx.x * blockDim.x + threadIdx.x;
  int stride = gridDim.x * blockDim.x;
  for (; i < n; i += stride) dst[i] = f2bf(src[i]);
}

// ---------- GEMM: C_bf[M,N] = act(A_bf[M,K] @ W_bf[N,K]^T + bias[N]) ----------
// 128x128 tile, BK=64, 256 threads (4 waves), global_load_lds staging (m97 structure)
template<bool RELU>
__global__ __launch_bounds__(256)
void gemm_bt(const unsigned short* __restrict__ A, const unsigned short* __restrict__ W,
             const float* __restrict__ bias, unsigned short* __restrict__ C,
             int N, int K) {
  __shared__ unsigned short sA[128 * 64];
  __shared__ unsigned short sB[128 * 64];
  const int tid = threadIdx.x;
  const int w = tid >> 6, lane = tid & 63;
  const int l15 = lane & 15, l4 = lane >> 4;
  const int nbn = N >> 7;
  const int bm = blockIdx.x / nbn, bn = blockIdx.x % nbn;

  f32x4 acc[4][4];
  const f32x4 fz = {0.f, 0.f, 0.f, 0.f};
#pragma unroll
  for (int i = 0; i < 4; i++)
#pragma unroll
    for (int j = 0; j < 4; j++) acc[i][j] = fz;

  const int nk = K >> 6;
  for (int bk = 0; bk < nk; ++bk) {
#pragma unroll
    for (int it = 0; it < 4; ++it) {
      int slot = it * 256 + tid;          // 1024 slots of 16B per tile
      int row = slot >> 3, c16 = slot & 7;
      const unsigned short* ga = A + (size_t)(bm * 128 + row) * K + bk * 64 + c16 * 8;
      const unsigned short* gb = W + (size_t)(bn * 128 + row) * K + bk * 64 + c16 * 8;
      unsigned ldsoff = (unsigned)(it * 256 + w * 64) * 16;  // wave-uniform; HW adds lane*16
      gload_lds16(ga, sA, ldsoff);
      gload_lds16(gb, sB, ldsoff);
    }
    __syncthreads();
#pragma unroll
    for (int kt = 0; kt < 2; ++kt) {
      bf16x8 af[4], bfr[4];
#pragma unroll
      for (int m = 0; m < 4; m++) {
        int row = ((w >> 1) * 64) + m * 16 + l15;
        af[m] = ld_bf8_g(&sA[row * 64 + kt * 32 + l4 * 8]);
      }
#pragma unroll
      for (int n = 0; n < 4; n++) {
        int row = ((w & 1) * 64) + n * 16 + l15;
        bfr[n] = ld_bf8_g(&sB[row * 64 + kt * 32 + l4 * 8]);
      }
#pragma unroll
      for (int m = 0; m < 4; m++)
#pragma unroll
        for (int n = 0; n < 4; n++)
          acc[m][n] = __builtin_amdgcn_mfma_f32_16x16x32_bf16(af[m], bfr[n], acc[m][n], 0, 0, 0);
    }
    __syncthreads();
  }

  const int r0 = bm * 128 + (w >> 1) * 64;
  const int c0 = bn * 128 + (w & 1) * 64;
#pragma unroll
  for (int n = 0; n < 4; n++) {
    int c = c0 + n * 16 + l15;
    float b = bias[c];
#pragma unroll
    for (int m = 0; m < 4; m++)
#pragma unroll
      for (int j = 0; j < 4; j++) {
        int r = r0 + m * 16 + l4 * 4 + j;
        float v = acc[m][n][j] + b;
        if (RELU) v = fmaxf(v, 0.f);
        C[(size_t)r * N + c] = f2bf(v);
      }
  }
}

// ---------- one GRU time step ----------
// grid = 32 WGs: [8 seq-groups of 32] x [4 H-groups of 128]; 256 threads (4 waves)
// wave w owns H-cols c0w..c0w+31 (2 n-tiles) x 3 gates; M = 32 seqs (2 m-tiles)
__global__ __launch_bounds__(256)
void gru_step(const unsigned short* __restrict__ hb_read,   // [256][512] bf16 (prev h)
              unsigned short* __restrict__ hb_write,        // [256][512] bf16 (new h)
              const unsigned short* __restrict__ whh,       // [1536][512] bf16
              const float* __restrict__ b_hh,               // [1536]
              const unsigned short* __restrict__ gi,        // [65536][1536] bf16 (incl b_ih)
              const float* __restrict__ h0f,                // [256][512] f32
              float* __restrict__ hout,                     // [65536][512] f32 (d_out h)
              int t) {
  __shared__ unsigned short sH[32 * 512];  // 32KB, XOR-swizzled
  const int tid = threadIdx.x;
  const int w = tid >> 6, lane = tid & 63, l15 = lane & 15, l4 = lane >> 4;
  const int mg = blockIdx.x >> 2;
  const int hg = blockIdx.x & 3;
  const int s0 = mg * 32;
  const int c0w = hg * 128 + w * 32;

  // stage prev-h tile (swizzled): each wave writes one row per iter, conflict-free
#pragma unroll
  for (int it = 0; it < 8; ++it) {
    int slot = it * 256 + tid;           // 2048 slots of 16B
    int row = slot >> 6, c16 = slot & 63;
    ushort8 v = *(const ushort8*)(hb_read + (size_t)(s0 + row) * 512 + c16 * 8);
    unsigned byte = ((unsigned)(row * 1024 + c16 * 16)) ^ ((unsigned)(row & 7) << 4);
    *(ushort8*)((char*)sH + byte) = v;
  }
  __syncthreads();

  f32x4 acc[2][3][2];
  const f32x4 fz = {0.f, 0.f, 0.f, 0.f};
#pragma unroll
  for (int m = 0; m < 2; m++)
#pragma unroll
    for (int g = 0; g < 3; g++)
#pragma unroll
      for (int c = 0; c < 2; c++) acc[m][g][c] = fz;

  for (int kt = 0; kt < 16; ++kt) {
    bf16x8 a[2];
#pragma unroll
    for (int m = 0; m < 2; m++) {
      int row = m * 16 + l15;
      unsigned byte = ((unsigned)(row * 1024 + kt * 64 + l4 * 16)) ^ ((unsigned)(row & 7) << 4);
      a[m] = ld_bf8_b((const char*)sH, byte);
    }
    bf16x8 b[3][2];
#pragma unroll
    for (int g = 0; g < 3; g++)
#pragma unroll
      for (int ct = 0; ct < 2; ct++) {
        int wrow = g * 512 + c0w + ct * 16 + l15;
        b[g][ct] = ld_bf8_g(whh + (size_t)wrow * 512 + kt * 32 + l4 * 8);
      }
#pragma unroll
    for (int m = 0; m < 2; m++)
#pragma unroll
      for (int g = 0; g < 3; g++)
#pragma unroll
        for (int ct = 0; ct < 2; ct++)
          acc[m][g][ct] = __builtin_amdgcn_mfma_f32_16x16x32_bf16(a[m], b[g][ct], acc[m][g][ct], 0, 0, 0);
  }

#pragma unroll
  for (int m = 0; m < 2; m++)
#pragma unroll
    for (int ct = 0; ct < 2; ct++)
#pragma unroll
      for (int j = 0; j < 4; j++) {
        int s = s0 + m * 16 + l4 * 4 + j;
        int c = c0w + ct * 16 + l15;
        float ghr = acc[m][0][ct][j] + b_hh[c];
        float ghz = acc[m][1][ct][j] + b_hh[512 + c];
        float ghn = acc[m][2][ct][j] + b_hh[1024 + c];
        size_t gib = ((size_t)s * TT + t) * G3;
        float ir = bf2f(gi[gib + c]);
        float iz = bf2f(gi[gib + 512 + c]);
        float in_ = bf2f(gi[gib + 1024 + c]);
        float r = 1.f / (1.f + __expf(-(ir + ghr)));
        float z = 1.f / (1.f + __expf(-(iz + ghz)));
        float n = tanhf(in_ + r * ghn);
        float hp = (t == 0) ? h0f[(size_t)s * 512 + c]
                            : hout[((size_t)s * TT + (t - 1)) * 512 + c];
        float hn = (1.f - z) * n + z * hp;
        hout[((size_t)s * TT + t) * 512 + c] = hn;
        hb_write[(size_t)s * 512 + c] = f2bf(hn);
      }
}

// ---------- decoder + softmax ----------
// grid = 1024 WGs, each: 64 rows x all 64 cols. A staged from fp32 h (d_out), converted.
__global__ __launch_bounds__(256)
void decoder_softmax(const float* __restrict__ hf,          // [65536][512] f32
                     const unsigned short* __restrict__ dwb, // [64][512] bf16
                     const float* __restrict__ dec_b,        // [64]
                     float* __restrict__ pi) {               // [65536][64] f32
  __shared__ unsigned short sH[64 * 512];  // 64KB, swizzled
  const int tid = threadIdx.x, w = tid >> 6, lane = tid & 63, l15 = lane & 15, l4 = lane >> 4;
  const size_t m0 = (size_t)blockIdx.x * 64;

#pragma unroll
  for (int it = 0; it < 16; ++it) {
    int slot = it * 256 + tid;           // 4096 slots of 16B
    int row = slot >> 6, c16 = slot & 63;
    const float* g = hf + (m0 + row) * 512 + c16 * 8;
    float4v v0 = *(const float4v*)g;
    float4v v1 = *(const float4v*)(g + 4);
    ushort8 u;
    u[0] = f2bf(v0[0]); u[1] = f2bf(v0[1]); u[2] = f2bf(v0[2]); u[3] = f2bf(v0[3]);
    u[4] = f2bf(v1[0]); u[5] = f2bf(v1[1]); u[6] = f2bf(v1[2]); u[7] = f2bf(v1[3]);
    unsigned byte = ((unsigned)(row * 1024 + c16 * 16)) ^ ((unsigned)(row & 7) << 4);
    *(ushort8*)((char*)sH + byte) = u;
  }
  __syncthreads();

  f32x4 acc[4];
  const f32x4 fz = {0.f, 0.f, 0.f, 0.f};
#pragma unroll
  for (int n = 0; n < 4; n++) acc[n] = fz;

  for (int kt = 0; kt < 16; ++kt) {
    int row = w * 16 + l15;
    unsigned byte = ((unsigned)(row * 1024 + kt * 64 + l4 * 16)) ^ ((unsigned)(row & 7) << 4);
    bf16x8 a = ld_bf8_b((const char*)sH, byte);
#pragma unroll
    for (int nt = 0; nt < 4; nt++) {
      bf16x8 b = ld_bf8_g(dwb + (size_t)(nt * 16 + l15) * 512 + kt * 32 + l4 * 8);
      acc[nt] = __builtin_amdgcn_mfma_f32_16x16x32_bf16(a, b, acc[nt], 0, 0, 0);
    }
  }

#pragma unroll
  for (int j = 0; j < 4; j++) {
    size_t r = m0 + w * 16 + l4 * 4 + j;
    float v[4];
    float mx = -1e30f;
#pragma unroll
    for (int nt = 0; nt < 4; nt++) {
      v[nt] = fmaxf(acc[nt][j] + dec_b[nt * 16 + l15], 0.f);
      mx = fmaxf(mx, v[nt]);
    }
#pragma unroll
    for (int msk = 1; msk <= 8; msk <<= 1) mx = fmaxf(mx, __shfl_xor(mx, msk));
    float s = 0.f;
#pragma unroll
    for (int nt = 0; nt < 4; nt++) { v[nt] = __expf(v[nt] - mx); s += v[nt]; }
#pragma unroll
    for (int msk = 1; msk <= 8; msk <<= 1) s += __shfl_xor(s, msk);
    float inv = 1.f / s;
#pragma unroll
    for (int nt = 0; nt < 4; nt++) pi[r * 64 + nt * 16 + l15] = v[nt] * inv;
  }
}

extern "C" void kernel_launch(void* const* d_in, const int* in_sizes, int n_in,
                              void* d_out, int out_size, void* d_ws, size_t ws_size,
                              hipStream_t stream) {
  const float* x     = (const float*)d_in[0];
  const float* h0    = (const float*)d_in[1];
  const float* enc_w = (const float*)d_in[2];
  const float* enc_b = (const float*)d_in[3];
  const float* w_ih  = (const float*)d_in[4];
  const float* w_hh  = (const float*)d_in[5];
  const float* b_ih  = (const float*)d_in[6];
  const float* b_hh  = (const float*)d_in[7];
  const float* dec_w = (const float*)d_in[8];
  const float* dec_b = (const float*)d_in[9];

  float* pi_out = (float*)d_out;                 // 4,194,304 floats
  float* h_out  = (float*)d_out + 4194304;       // 33,554,432 floats

  unsigned short* ws = (unsigned short*)d_ws;
  size_t off = 0;
  unsigned short* x_bf    = ws + off; off += (size_t)MROWS * VV;   // 8.4M
  unsigned short* enc_bf  = ws + off; off += (size_t)MROWS * EE;   // 33.6M
  unsigned short* gi_bf   = ws + off; off += (size_t)MROWS * G3;   // 100.7M
  unsigned short* encw_bf = ws + off; off += (size_t)EE * VV;
  unsigned short* wih_bf  = ws + off; off += (size_t)G3 * EE;
  unsigned short* whh_bf  = ws + off; off += (size_t)G3 * HH;
  unsigned short* decw_bf = ws + off; off += (size_t)NA * HH;
  unsigned short* hb0     = ws + off; off += (size_t)NSEQ * HH;
  unsigned short* hb1     = ws + off; off += (size_t)NSEQ * HH;
  (void)ws_size; (void)in_sizes; (void)n_in; (void)out_size;

  auto cast = [&](const float* s, unsigned short* d, int n) {
    int blocks = (n + 255) / 256; if (blocks > 2048) blocks = 2048;
    cast_f32_bf16<<<blocks, 256, 0, stream>>>(s, d, n);
  };
  cast(x, x_bf, MROWS * VV);
  cast(enc_w, encw_bf, EE * VV);
  cast(w_ih, wih_bf, G3 * EE);
  cast(w_hh, whh_bf, G3 * HH);
  cast(dec_w, decw_bf, NA * HH);
  cast(h0, hb0, NSEQ * HH);

  // encoder: [65536,128] @ [512,128]^T, ReLU -> enc_bf
  gemm_bt<true><<<(MROWS / 128) * (EE / 128), 256, 0, stream>>>(x_bf, encw_bf, enc_b, enc_bf, EE, VV);
  // gi: [65536,512] @ [1536,512]^T + b_ih -> gi_bf
  gemm_bt<false><<<(MROWS / 128) * (G3 / 128), 256, 0, stream>>>(enc_bf, wih_bf, b_ih, gi_bf, G3, EE);

  for (int t = 0; t < TT; ++t) {
    const unsigned short* hr = (t & 1) ? hb1 : hb0;
    unsigned short* hw = (t & 1) ? hb0 : hb1;
    gru_step<<<32, 256, 0, stream>>>(hr, hw, whh_bf, b_hh, gi_bf, h0, h_out, t);
  }

  decoder_softmax<<<1024, 256, 0, stream>>>(h_out, decw_bf, dec_b, pi_out);
}

// Round 2
// 3904.935 us; speedup vs baseline: 1.3848x; 1.3848x over previous
//
#include <hip/hip_runtime.h>
#include <hip/hip_bf16.h>

typedef __bf16 bf16x8 __attribute__((ext_vector_type(8)));
typedef float f32x4 __attribute__((ext_vector_type(4)));
typedef unsigned short ushort8 __attribute__((ext_vector_type(8)));
typedef float float4v __attribute__((ext_vector_type(4)));

#define DEVI __device__ __forceinline__

// ---- sizes (compile-time) ----
#define NSEQ 256      // A_*BS
#define TT 256        // T
#define VV 128        // V
#define EE 512        // E
#define HH 512        // H
#define NA 64
#define MROWS 65536   // NSEQ*T
#define G3 1536       // 3*H

DEVI unsigned short f2bf(float f) {
  union { float f; unsigned u; } v; v.f = f;
  unsigned r = v.u + 0x7fffu + ((v.u >> 16) & 1u);
  return (unsigned short)(r >> 16);
}
DEVI float bf2f(unsigned short s) {
  union { unsigned u; float f; } v; v.u = ((unsigned)s) << 16;
  return v.f;
}
DEVI bf16x8 ld_bf8_g(const unsigned short* p) {
  ushort8 v = *(const ushort8*)p;
  return __builtin_bit_cast(bf16x8, v);
}
DEVI bf16x8 ld_bf8_b(const char* base, unsigned byte) {
  ushort8 v = *(const ushort8*)(base + byte);
  return __builtin_bit_cast(bf16x8, v);
}
DEVI void gload_lds16(const void* g, unsigned short* lds_base, unsigned lds_byte_off) {
  __builtin_amdgcn_global_load_lds(
      (const __attribute__((address_space(1))) unsigned int*)g,
      (__attribute__((address_space(3))) unsigned int*)(void*)((char*)lds_base + lds_byte_off),
      16, 0, 0);
}

// ---------- cast fp32 -> bf16(raw u16) ----------
__global__ void cast_f32_bf16(const float* __restrict__ src, unsigned short* __restrict__ dst, int n) {
  int i = blockIdx.x * blockDim.x + threadIdx.x;
  int stride = gridDim.x * blockDim.x;
  for (; i < n; i += stride) dst[i] = f2bf(src[i]);
}

__global__ void zero_u32(unsigned int* __restrict__ p, int n) {
  int i = blockIdx.x * blockDim.x + threadIdx.x;
  if (i < n) p[i] = 0u;
}

// ---------- GEMM: C_bf[M,N] = act(A_bf[M,K] @ W_bf[N,K]^T + bias[N]) ----------
template<bool RELU>
__global__ __launch_bounds__(256)
void gemm_bt(const unsigned short* __restrict__ A, const unsigned short* __restrict__ W,
             const float* __restrict__ bias, unsigned short* __restrict__ C,
             int N, int K) {
  __shared__ unsigned short sA[128 * 64];
  __shared__ unsigned short sB[128 * 64];
  const int tid = threadIdx.x;
  const int w = tid >> 6, lane = tid & 63;
  const int l15 = lane & 15, l4 = lane >> 4;
  const int nbn = N >> 7;
  const int bm = blockIdx.x / nbn, bn = blockIdx.x % nbn;

  f32x4 acc[4][4];
  const f32x4 fz = {0.f, 0.f, 0.f, 0.f};
#pragma unroll
  for (int i = 0; i < 4; i++)
#pragma unroll
    for (int j = 0; j < 4; j++) acc[i][j] = fz;

  const int nk = K >> 6;
  for (int bk = 0; bk < nk; ++bk) {
#pragma unroll
    for (int it = 0; it < 4; ++it) {
      int slot = it * 256 + tid;
      int row = slot >> 3, c16 = slot & 7;
      const unsigned short* ga = A + (size_t)(bm * 128 + row) * K + bk * 64 + c16 * 8;
      const unsigned short* gb = W + (size_t)(bn * 128 + row) * K + bk * 64 + c16 * 8;
      unsigned ldsoff = (unsigned)(it * 256 + w * 64) * 16;
      gload_lds16(ga, sA, ldsoff);
      gload_lds16(gb, sB, ldsoff);
    }
    __syncthreads();
#pragma unroll
    for (int kt = 0; kt < 2; ++kt) {
      bf16x8 af[4], bfr[4];
#pragma unroll
      for (int m = 0; m < 4; m++) {
        int row = ((w >> 1) * 64) + m * 16 + l15;
        af[m] = ld_bf8_g(&sA[row * 64 + kt * 32 + l4 * 8]);
      }
#pragma unroll
      for (int n = 0; n < 4; n++) {
        int row = ((w & 1) * 64) + n * 16 + l15;
        bfr[n] = ld_bf8_g(&sB[row * 64 + kt * 32 + l4 * 8]);
      }
#pragma unroll
      for (int m = 0; m < 4; m++)
#pragma unroll
        for (int n = 0; n < 4; n++)
          acc[m][n] = __builtin_amdgcn_mfma_f32_16x16x32_bf16(af[m], bfr[n], acc[m][n], 0, 0, 0);
    }
    __syncthreads();
  }

  const int r0 = bm * 128 + (w >> 1) * 64;
  const int c0 = bn * 128 + (w & 1) * 64;
#pragma unroll
  for (int n = 0; n < 4; n++) {
    int c = c0 + n * 16 + l15;
    float b = bias[c];
#pragma unroll
    for (int m = 0; m < 4; m++)
#pragma unroll
      for (int j = 0; j < 4; j++) {
        int r = r0 + m * 16 + l4 * 4 + j;
        float v = acc[m][n][j] + b;
        if (RELU) v = fmaxf(v, 0.f);
        C[(size_t)r * N + c] = f2bf(v);
      }
  }
}

// ---------- persistent GRU scan ----------
// 256 WGs = 16 seq-groups x 16 col-WGs; 256 threads (4 waves) each.
// Each WG: 16 seqs x 32 h-cols (x3 gates = 96 whh rows, LDS-resident).
// Per-group monotonic atomic barrier; bf16 ping-pong h exchange; fp32 carry in regs.
// LDS 124KB/WG => max 1 WG/CU => all 256 WGs co-resident by resource exhaustion.
#define GRU_LDS_BYTES (124 * 1024)

__global__ __launch_bounds__(256, 1)
void gru_persistent(const unsigned short* __restrict__ whh,
                    const float* __restrict__ b_hh,
                    const unsigned short* __restrict__ gi,
                    const float* __restrict__ h0f,
                    unsigned short* __restrict__ hbA,   // parity 0 writes
                    unsigned short* __restrict__ hbB,   // parity 1 writes (pre-filled with f2bf(h0))
                    float* __restrict__ hout,
                    unsigned int* __restrict__ cnt_base) {
  extern __shared__ char lds[];
  unsigned short* sW = (unsigned short*)lds;               // [96][512] bf16, swizzled (96KB)
  unsigned short* sH = (unsigned short*)(lds + 96 * 1024); // [16][512] bf16, swizzled (16KB)
  float* sP = (float*)(lds + 112 * 1024);                  // [6 nt][2 kh][16][16] f32 (12KB)

  const int tid = threadIdx.x;
  const int w = tid >> 6, lane = tid & 63, l15 = lane & 15, l4 = lane >> 4;
  const int sg = blockIdx.x >> 4, cg = blockIdx.x & 15;
  const int s0 = sg * 16;
  const int c0 = cg * 32;
  unsigned int* cnt = cnt_base + sg * 32;  // 128B-spaced per-group counter

  // ---- one-time: stage whh slice (rows: gate*512 + c0 + (0..31)) ----
  for (int it = 0; it < 24; ++it) {
    int slot = it * 256 + tid;              // 6144 slots of 16B
    int lcr = slot >> 6, c16 = slot & 63;   // lcr 0..95
    int grow = (lcr >> 5) * 512 + c0 + (lcr & 31);
    ushort8 v = *(const ushort8*)(whh + (size_t)grow * 512 + c16 * 8);
    unsigned byte = ((unsigned)(lcr * 1024 + c16 * 16)) ^ ((unsigned)(lcr & 7) << 4);
    *(ushort8*)((char*)sW + byte) = v;
  }

  // ---- per-thread epilogue constants: elems (i, hc) and (i, hc+16) ----
  const int i = tid >> 4, hc = tid & 15;
  const int s = s0 + i;
  float bias[2][3], hp[2];
#pragma unroll
  for (int e = 0; e < 2; ++e) {
    int c = c0 + hc + e * 16;
#pragma unroll
    for (int g = 0; g < 3; ++g) bias[e][g] = b_hh[g * 512 + c];
    hp[e] = h0f[(size_t)s * HH + c];
  }
  const size_t gib = (size_t)s * TT * G3 + c0 + hc;  // + t*G3 + gate*512 + e*16
  const size_t hob = (size_t)s * TT * HH + c0 + hc;  // + t*HH + e*16
  const size_t xwb = (size_t)s * HH + c0 + hc;       // + e*16

  const int kh = w >> 1, pp = w & 1;

  __syncthreads();  // sW ready

#pragma unroll 1
  for (int t = 0; t < TT; ++t) {
    const unsigned short* rb = (t & 1) ? hbA : hbB;  // h_{t-1}
    unsigned short* wbuf = (t & 1) ? hbB : hbA;      // h_t

    // prefetch gi(t) — independent of barrier, overlaps spin
    const unsigned short* gp = gi + gib + (size_t)t * G3;
    float gi_v[2][3];
#pragma unroll
    for (int e = 0; e < 2; ++e) {
      gi_v[e][0] = bf2f(gp[e * 16]);
      gi_v[e][1] = bf2f(gp[512 + e * 16]);
      gi_v[e][2] = bf2f(gp[1024 + e * 16]);
    }

    if (t > 0) {
      if (tid == 0) {
        unsigned target = 16u * (unsigned)t;
        while (__hip_atomic_load(cnt, __ATOMIC_ACQUIRE, __HIP_MEMORY_SCOPE_AGENT) < target)
          __builtin_amdgcn_s_sleep(2);
      }
      __syncthreads();
    }

    // stage h_{t-1} [16][512] -> sH (swizzled)
#pragma unroll
    for (int it = 0; it < 4; ++it) {
      int slot = it * 256 + tid;
      int row = slot >> 6, c16 = slot & 63;
      ushort8 v = *(const ushort8*)(rb + (size_t)(s0 + row) * HH + c16 * 8);
      unsigned byte = ((unsigned)(row * 1024 + c16 * 16)) ^ ((unsigned)(row & 7) << 4);
      *(ushort8*)((char*)sH + byte) = v;
    }
    __syncthreads();

    // MFMA: wave (kh, pp): K-half kh (8 k-steps), n-tiles pp*3..pp*3+2
    f32x4 acc[3];
    const f32x4 fz = {0.f, 0.f, 0.f, 0.f};
    acc[0] = fz; acc[1] = fz; acc[2] = fz;
#pragma unroll
    for (int ktl = 0; ktl < 8; ++ktl) {
      int ktg = kh * 8 + ktl;
      unsigned abyte = ((unsigned)(l15 * 1024 + ktg * 64 + l4 * 16)) ^ ((unsigned)(l15 & 7) << 4);
      bf16x8 a = ld_bf8_b((const char*)sH, abyte);
#pragma unroll
      for (int n3 = 0; n3 < 3; ++n3) {
        int lcr = (pp * 3 + n3) * 16 + l15;
        unsigned bbyte = ((unsigned)(lcr * 1024 + ktg * 64 + l4 * 16)) ^ ((unsigned)(lcr & 7) << 4);
        bf16x8 b = ld_bf8_b((const char*)sW, bbyte);
        acc[n3] = __builtin_amdgcn_mfma_f32_16x16x32_bf16(a, b, acc[n3], 0, 0, 0);
      }
    }
    // write K-half partials
#pragma unroll
    for (int n3 = 0; n3 < 3; ++n3) {
      int nt = pp * 3 + n3;
#pragma unroll
      for (int j = 0; j < 4; ++j)
        sP[(nt * 2 + kh) * 256 + (l4 * 4 + j) * 16 + l15] = acc[n3][j];
    }
    __syncthreads();

    // epilogue: 2 elems/thread; gh[g] for elem e lives in n-tile g*2+e, col hc, row i
    float hn[2];
#pragma unroll
    for (int e = 0; e < 2; ++e) {
      float gh[3];
#pragma unroll
      for (int g = 0; g < 3; ++g) {
        int nt = g * 2 + e;
        gh[g] = sP[(nt * 2 + 0) * 256 + i * 16 + hc]
              + sP[(nt * 2 + 1) * 256 + i * 16 + hc] + bias[e][g];
      }
      float r = 1.f / (1.f + __expf(-(gi_v[e][0] + gh[0])));
      float z = 1.f / (1.f + __expf(-(gi_v[e][1] + gh[1])));
      float nx = gi_v[e][2] + r * gh[2];
      float ex = __expf(2.f * nx);
      float n = 1.f - 2.f / (ex + 1.f);   // tanh, inf-safe
      hn[e] = (1.f - z) * n + z * hp[e];
      hp[e] = hn[e];
      hout[hob + (size_t)t * HH + e * 16] = hn[e];
      wbuf[xwb + e * 16] = f2bf(hn[e]);
    }
    __syncthreads();  // all exchange writes done; also protects sH/sP WAR
    if (tid == 0) {
      __hip_atomic_fetch_add(cnt, 1u, __ATOMIC_RELEASE, __HIP_MEMORY_SCOPE_AGENT);
    }
  }
}

// ---------- decoder + softmax ----------
__global__ __launch_bounds__(256)
void decoder_softmax(const float* __restrict__ hf,
                     const unsigned short* __restrict__ dwb,
                     const float* __restrict__ dec_b,
                     float* __restrict__ pi) {
  __shared__ unsigned short sH[64 * 512];
  const int tid = threadIdx.x, w = tid >> 6, lane = tid & 63, l15 = lane & 15, l4 = lane >> 4;
  const size_t m0 = (size_t)blockIdx.x * 64;

#pragma unroll
  for (int it = 0; it < 16; ++it) {
    int slot = it * 256 + tid;
    int row = slot >> 6, c16 = slot & 63;
    const float* g = hf + (m0 + row) * 512 + c16 * 8;
    float4v v0 = *(const float4v*)g;
    float4v v1 = *(const float4v*)(g + 4);
    ushort8 u;
    u[0] = f2bf(v0[0]); u[1] = f2bf(v0[1]); u[2] = f2bf(v0[2]); u[3] = f2bf(v0[3]);
    u[4] = f2bf(v1[0]); u[5] = f2bf(v1[1]); u[6] = f2bf(v1[2]); u[7] = f2bf(v1[3]);
    unsigned byte = ((unsigned)(row * 1024 + c16 * 16)) ^ ((unsigned)(row & 7) << 4);
    *(ushort8*)((char*)sH + byte) = u;
  }
  __syncthreads();

  f32x4 acc[4];
  const f32x4 fz = {0.f, 0.f, 0.f, 0.f};
#pragma unroll
  for (int n = 0; n < 4; n++) acc[n] = fz;

  for (int kt = 0; kt < 16; ++kt) {
    int row = w * 16 + l15;
    unsigned byte = ((unsigned)(row * 1024 + kt * 64 + l4 * 16)) ^ ((unsigned)(row & 7) << 4);
    bf16x8 a = ld_bf8_b((const char*)sH, byte);
#pragma unroll
    for (int nt = 0; nt < 4; nt++) {
      bf16x8 b = ld_bf8_g(dwb + (size_t)(nt * 16 + l15) * 512 + kt * 32 + l4 * 8);
      acc[nt] = __builtin_amdgcn_mfma_f32_16x16x32_bf16(a, b, acc[nt], 0, 0, 0);
    }
  }

#pragma unroll
  for (int j = 0; j < 4; j++) {
    size_t r = m0 + w * 16 + l4 * 4 + j;
    float v[4];
    float mx = -1e30f;
#pragma unroll
    for (int nt = 0; nt < 4; nt++) {
      v[nt] = fmaxf(acc[nt][j] + dec_b[nt * 16 + l15], 0.f);
      mx = fmaxf(mx, v[nt]);
    }
#pragma unroll
    for (int msk = 1; msk <= 8; msk <<= 1) mx = fmaxf(mx, __shfl_xor(mx, msk));
    float s = 0.f;
#pragma unroll
    for (int nt = 0; nt < 4; nt++) { v[nt] = __expf(v[nt] - mx); s += v[nt]; }
#pragma unroll
    for (int msk = 1; msk <= 8; msk <<= 1) s += __shfl_xor(s, msk);
    float inv = 1.f / s;
#pragma unroll
    for (int nt = 0; nt < 4; nt++) pi[r * 64 + nt * 16 + l15] = v[nt] * inv;
  }
}

extern "C" void kernel_launch(void* const* d_in, const int* in_sizes, int n_in,
                              void* d_out, int out_size, void* d_ws, size_t ws_size,
                              hipStream_t stream) {
  const float* x     = (const float*)d_in[0];
  const float* h0    = (const float*)d_in[1];
  const float* enc_w = (const float*)d_in[2];
  const float* enc_b = (const float*)d_in[3];
  const float* w_ih  = (const float*)d_in[4];
  const float* w_hh  = (const float*)d_in[5];
  const float* b_ih  = (const float*)d_in[6];
  const float* b_hh  = (const float*)d_in[7];
  const float* dec_w = (const float*)d_in[8];
  const float* dec_b = (const float*)d_in[9];

  float* pi_out = (float*)d_out;
  float* h_out  = (float*)d_out + 4194304;

  unsigned short* ws = (unsigned short*)d_ws;
  size_t off = 0;
  unsigned short* x_bf    = ws + off; off += (size_t)MROWS * VV;
  unsigned short* enc_bf  = ws + off; off += (size_t)MROWS * EE;
  unsigned short* gi_bf   = ws + off; off += (size_t)MROWS * G3;
  unsigned short* encw_bf = ws + off; off += (size_t)EE * VV;
  unsigned short* wih_bf  = ws + off; off += (size_t)G3 * EE;
  unsigned short* whh_bf  = ws + off; off += (size_t)G3 * HH;
  unsigned short* decw_bf = ws + off; off += (size_t)NA * HH;
  unsigned short* hb0     = ws + off; off += (size_t)NSEQ * HH;
  unsigned short* hb1     = ws + off; off += (size_t)NSEQ * HH;
  unsigned int*   cnt32   = (unsigned int*)(ws + off); off += 1024;  // 512 u32
  (void)ws_size; (void)in_sizes; (void)n_in; (void)out_size;

  // allow >64KB dynamic LDS for the persistent kernel (capture-safe host call)
  hipFuncSetAttribute((const void*)gru_persistent,
                      hipFuncAttributeMaxDynamicSharedMemorySize, GRU_LDS_BYTES);

  auto cast = [&](const float* s, unsigned short* d, int n) {
    int blocks = (n + 255) / 256; if (blocks > 2048) blocks = 2048;
    cast_f32_bf16<<<blocks, 256, 0, stream>>>(s, d, n);
  };
  cast(x, x_bf, MROWS * VV);
  cast(enc_w, encw_bf, EE * VV);
  cast(w_ih, wih_bf, G3 * EE);
  cast(w_hh, whh_bf, G3 * HH);
  cast(dec_w, decw_bf, NA * HH);
  cast(h0, hb1, NSEQ * HH);              // t=0 reads hbB == hb1

  zero_u32<<<1, 512, 0, stream>>>(cnt32, 512);

  gemm_bt<true><<<(MROWS / 128) * (EE / 128), 256, 0, stream>>>(x_bf, encw_bf, enc_b, enc_bf, EE, VV);
  gemm_bt<false><<<(MROWS / 128) * (G3 / 128), 256, 0, stream>>>(enc_bf, wih_bf, b_ih, gi_bf, G3, EE);

  gru_persistent<<<dim3(256), dim3(256), GRU_LDS_BYTES, stream>>>(
      whh_bf, b_hh, gi_bf, h0, hb0, hb1, h_out, cnt32);

  decoder_softmax<<<1024, 256, 0, stream>>>(h_out, decw_bf, dec_b, pi_out);
}

// Round 3
// 1644.986 us; speedup vs baseline: 3.2873x; 2.3738x over previous
//
#include <hip/hip_runtime.h>
#include <hip/hip_bf16.h>

typedef __bf16 bf16x8 __attribute__((ext_vector_type(8)));
typedef float f32x4 __attribute__((ext_vector_type(4)));
typedef unsigned short ushort8 __attribute__((ext_vector_type(8)));
typedef float float4v __attribute__((ext_vector_type(4)));
typedef unsigned long long u64;
typedef unsigned int u32;

#define DEVI __device__ __forceinline__

// ---- sizes (compile-time) ----
#define NSEQ 256      // A_*BS
#define TT 256        // T
#define VV 128        // V
#define EE 512        // E
#define HH 512        // H
#define NA 64
#define MROWS 65536   // NSEQ*T
#define G3 1536       // 3*H

DEVI unsigned short f2bf(float f) {
  union { float f; unsigned u; } v; v.f = f;
  unsigned r = v.u + 0x7fffu + ((v.u >> 16) & 1u);
  return (unsigned short)(r >> 16);
}
DEVI float bf2f(unsigned short s) {
  union { unsigned u; float f; } v; v.u = ((unsigned)s) << 16;
  return v.f;
}
DEVI bf16x8 ld_bf8_g(const unsigned short* p) {
  ushort8 v = *(const ushort8*)p;
  return __builtin_bit_cast(bf16x8, v);
}
DEVI bf16x8 ld_bf8_b(const char* base, unsigned byte) {
  ushort8 v = *(const ushort8*)(base + byte);
  return __builtin_bit_cast(bf16x8, v);
}
DEVI void gload_lds16(const void* g, unsigned short* lds_base, unsigned lds_byte_off) {
  __builtin_amdgcn_global_load_lds(
      (const __attribute__((address_space(1))) unsigned int*)g,
      (__attribute__((address_space(3))) unsigned int*)(void*)((char*)lds_base + lds_byte_off),
      16, 0, 0);
}

// ---------- cast fp32 -> bf16(raw u16) ----------
__global__ void cast_f32_bf16(const float* __restrict__ src, unsigned short* __restrict__ dst, int n) {
  int i = blockIdx.x * blockDim.x + threadIdx.x;
  int stride = gridDim.x * blockDim.x;
  for (; i < n; i += stride) dst[i] = f2bf(src[i]);
}

__global__ void zero_u32(u32* __restrict__ p, int n) {
  int i = blockIdx.x * blockDim.x + threadIdx.x;
  if (i < n) p[i] = 0u;
}

// ---------- GEMM: C_bf[M,N] = act(A_bf[M,K] @ W_bf[N,K]^T + bias[N]) ----------
template<bool RELU>
__global__ __launch_bounds__(256)
void gemm_bt(const unsigned short* __restrict__ A, const unsigned short* __restrict__ W,
             const float* __restrict__ bias, unsigned short* __restrict__ C,
             int N, int K) {
  __shared__ unsigned short sA[128 * 64];
  __shared__ unsigned short sB[128 * 64];
  const int tid = threadIdx.x;
  const int w = tid >> 6, lane = tid & 63;
  const int l15 = lane & 15, l4 = lane >> 4;
  const int nbn = N >> 7;
  const int bm = blockIdx.x / nbn, bn = blockIdx.x % nbn;

  f32x4 acc[4][4];
  const f32x4 fz = {0.f, 0.f, 0.f, 0.f};
#pragma unroll
  for (int i = 0; i < 4; i++)
#pragma unroll
    for (int j = 0; j < 4; j++) acc[i][j] = fz;

  const int nk = K >> 6;
  for (int bk = 0; bk < nk; ++bk) {
#pragma unroll
    for (int it = 0; it < 4; ++it) {
      int slot = it * 256 + tid;
      int row = slot >> 3, c16 = slot & 7;
      const unsigned short* ga = A + (size_t)(bm * 128 + row) * K + bk * 64 + c16 * 8;
      const unsigned short* gb = W + (size_t)(bn * 128 + row) * K + bk * 64 + c16 * 8;
      unsigned ldsoff = (unsigned)(it * 256 + w * 64) * 16;
      gload_lds16(ga, sA, ldsoff);
      gload_lds16(gb, sB, ldsoff);
    }
    __syncthreads();
#pragma unroll
    for (int kt = 0; kt < 2; ++kt) {
      bf16x8 af[4], bfr[4];
#pragma unroll
      for (int m = 0; m < 4; m++) {
        int row = ((w >> 1) * 64) + m * 16 + l15;
        af[m] = ld_bf8_g(&sA[row * 64 + kt * 32 + l4 * 8]);
      }
#pragma unroll
      for (int n = 0; n < 4; n++) {
        int row = ((w & 1) * 64) + n * 16 + l15;
        bfr[n] = ld_bf8_g(&sB[row * 64 + kt * 32 + l4 * 8]);
      }
#pragma unroll
      for (int m = 0; m < 4; m++)
#pragma unroll
        for (int n = 0; n < 4; n++)
          acc[m][n] = __builtin_amdgcn_mfma_f32_16x16x32_bf16(af[m], bfr[n], acc[m][n], 0, 0, 0);
    }
    __syncthreads();
  }

  const int r0 = bm * 128 + (w >> 1) * 64;
  const int c0 = bn * 128 + (w & 1) * 64;
#pragma unroll
  for (int n = 0; n < 4; n++) {
    int c = c0 + n * 16 + l15;
    float b = bias[c];
#pragma unroll
    for (int m = 0; m < 4; m++)
#pragma unroll
      for (int j = 0; j < 4; j++) {
        int r = r0 + m * 16 + l4 * 4 + j;
        float v = acc[m][n][j] + b;
        if (RELU) v = fmaxf(v, 0.f);
        C[(size_t)r * N + c] = f2bf(v);
      }
  }
}

// ---------- persistent GRU scan (fence-free relaxed-atomic exchange) ----------
// 128 WGs = 8 seq-groups(32 seqs) x 16 col-WGs(32 cols). 256 threads = 4 waves.
// wave (mm = w>>1, e = w&1): m-half mm (16 seqs), col-half e (16 cols), ALL 3 gates,
// full K=512 -> each thread locally owns r,z,n for its 4 (row,col) outputs.
// LDS: sW[96][512] bf16 (96KB, swizzled) only => 1 WG/CU => all 128 co-resident.
// Exchange h via relaxed agent atomics (coherent, NO buffer_inv/wbl2 on the chain).
#define GRU_LDS_BYTES (96 * 1024)

__global__ __launch_bounds__(256, 1)
void gru_scan(const unsigned short* __restrict__ whh,
              const float* __restrict__ b_hh,
              const unsigned short* __restrict__ gi,
              const float* __restrict__ h0f,
              unsigned short* __restrict__ hbA,   // parity 0 writes
              unsigned short* __restrict__ hbB,   // parity 1 writes (pre-filled f2bf(h0))
              float* __restrict__ hout,
              u32* __restrict__ cnt_base) {
  extern __shared__ char lds[];
  unsigned short* sW = (unsigned short*)lds;   // [96][512] bf16, swizzled

  const int tid = threadIdx.x;
  const int w = tid >> 6, lane = tid & 63, l15 = lane & 15, l4 = lane >> 4;
  const int sg = blockIdx.x >> 4, cg = blockIdx.x & 15;
  const int s0 = sg * 32;
  const int c0 = cg * 32;
  const int mm = w >> 1, e = w & 1;
  u32* cnt = cnt_base + sg * 32;               // 128B-spaced per-group counter

  // ---- one-time: stage whh slice rows (gate*512 + c0 + 0..31) ----
  for (int it = 0; it < 24; ++it) {
    int slot = it * 256 + tid;                 // 6144 slots of 16B
    int lcr = slot >> 6, c16 = slot & 63;      // lcr 0..95
    int grow = (lcr >> 5) * 512 + c0 + (lcr & 31);
    ushort8 v = *(const ushort8*)(whh + (size_t)grow * 512 + c16 * 8);
    unsigned byte = ((unsigned)(lcr * 1024 + c16 * 16)) ^ ((unsigned)(lcr & 7) << 4);
    *(ushort8*)((char*)sW + byte) = v;
  }

  // ---- per-thread constants ----
  const int c = c0 + e * 16 + l15;             // output col
  int rj[4];
#pragma unroll
  for (int j = 0; j < 4; ++j) rj[j] = s0 + mm * 16 + l4 * 4 + j;
  float bias0 = b_hh[c], bias1 = b_hh[512 + c], bias2 = b_hh[1024 + c];
  float hp[4];
#pragma unroll
  for (int j = 0; j < 4; ++j) hp[j] = h0f[(size_t)rj[j] * HH + c];
  size_t houtb[4], gib[4];
#pragma unroll
  for (int j = 0; j < 4; ++j) {
    houtb[j] = (size_t)rj[j] * TT * HH + c;
    gib[j]   = (size_t)rj[j] * TT * G3 + c;
  }
  const int arow = s0 + mm * 16 + l15;         // A-fragment row for this lane
  const unsigned storej = (l15 & 1);           // even lanes store j=0,1; odd j=2,3

  __syncthreads();  // sW ready

#pragma unroll 1
  for (int t = 0; t < TT; ++t) {
    const unsigned short* rb = (t & 1) ? hbA : hbB;
    unsigned short* wb = (t & 1) ? hbB : hbA;

    // prefetch gi(t) — plain cached loads, independent of the barrier
    float gv0[4], gv1[4], gv2[4];
#pragma unroll
    for (int j = 0; j < 4; ++j) {
      const unsigned short* gp = gi + gib[j] + (size_t)t * G3;
      gv0[j] = bf2f(gp[0]);
      gv1[j] = bf2f(gp[512]);
      gv2[j] = bf2f(gp[1024]);
    }

    if (t > 0) {
      if (tid == 0) {
        unsigned target = 16u * (unsigned)t;
        while (__hip_atomic_load(cnt, __ATOMIC_RELAXED, __HIP_MEMORY_SCOPE_AGENT) < target)
          __builtin_amdgcn_s_sleep(1);
      }
      __syncthreads();   // nobody reads h_{t-1} before it is known complete
    }

    // ---- A-fragments direct-to-reg: 32 relaxed u64 atomic loads (coherent) ----
    const unsigned short* ap = rb + (size_t)arow * HH + l4 * 8;
    u64 av[32];
#pragma unroll
    for (int ktg = 0; ktg < 16; ++ktg) {
      av[2 * ktg]     = __hip_atomic_load((const u64*)(ap + ktg * 32),
                                          __ATOMIC_RELAXED, __HIP_MEMORY_SCOPE_AGENT);
      av[2 * ktg + 1] = __hip_atomic_load((const u64*)(ap + ktg * 32 + 4),
                                          __ATOMIC_RELAXED, __HIP_MEMORY_SCOPE_AGENT);
    }

    // ---- MFMA: 16 k-steps x 3 gates, full K, no partial reduce ----
    f32x4 acc[3];
    const f32x4 fz = {0.f, 0.f, 0.f, 0.f};
    acc[0] = fz; acc[1] = fz; acc[2] = fz;
#pragma unroll
    for (int ktg = 0; ktg < 16; ++ktg) {
      union { u64 q[2]; bf16x8 v; } ua;
      ua.q[0] = av[2 * ktg]; ua.q[1] = av[2 * ktg + 1];
      bf16x8 a = ua.v;
#pragma unroll
      for (int g = 0; g < 3; ++g) {
        int lcr = g * 32 + e * 16 + l15;
        unsigned byte = ((unsigned)(lcr * 1024 + ktg * 64 + l4 * 16)) ^ ((unsigned)(lcr & 7) << 4);
        bf16x8 b = ld_bf8_b((const char*)sW, byte);
        acc[g] = __builtin_amdgcn_mfma_f32_16x16x32_bf16(a, b, acc[g], 0, 0, 0);
      }
    }

    // ---- epilogue: each thread owns r,z,n for 4 (row, col=c) outputs ----
    float hn[4];
#pragma unroll
    for (int j = 0; j < 4; ++j) {
      float gh0 = acc[0][j] + bias0;
      float gh1 = acc[1][j] + bias1;
      float gh2 = acc[2][j] + bias2;
      float rr = 1.f / (1.f + __expf(-(gv0[j] + gh0)));
      float zz = 1.f / (1.f + __expf(-(gv1[j] + gh1)));
      float nx = gv2[j] + rr * gh2;
      float ex = __expf(2.f * nx);
      float nn = 1.f - 2.f / (ex + 1.f);       // tanh, inf-safe
      hn[j] = (1.f - zz) * nn + zz * hp[j];
      hp[j] = hn[j];
      hout[houtb[j] + (size_t)t * HH] = hn[j]; // plain cached store (flushed at kernel end)
    }

    // ---- exchange: pack col-pairs via shfl, relaxed u32 atomic stores ----
#pragma unroll
    for (int j = 0; j < 4; ++j) {
      u32 my = f2bf(hn[j]);
      u32 oth = (u32)__shfl_xor((int)my, 1);
      u32 word = (l15 & 1) ? ((oth & 0xffffu) | (my << 16))
                           : ((my & 0xffffu) | (oth << 16));
      if ((unsigned)(j >> 1) == storej) {
        u32* dst = (u32*)(wb + (size_t)rj[j] * HH + (c & ~1));
        __hip_atomic_store(dst, word, __ATOMIC_RELAXED, __HIP_MEMORY_SCOPE_AGENT);
      }
    }

    __syncthreads();  // drains vmcnt: all exchange stores ACKed at coherence point
    if (tid == 0)
      __hip_atomic_fetch_add(cnt, 1u, __ATOMIC_RELAXED, __HIP_MEMORY_SCOPE_AGENT);
  }
}

// ---------- decoder + softmax ----------
__global__ __launch_bounds__(256)
void decoder_softmax(const float* __restrict__ hf,
                     const unsigned short* __restrict__ dwb,
                     const float* __restrict__ dec_b,
                     float* __restrict__ pi) {
  __shared__ unsigned short sH[64 * 512];
  const int tid = threadIdx.x, w = tid >> 6, lane = tid & 63, l15 = lane & 15, l4 = lane >> 4;
  const size_t m0 = (size_t)blockIdx.x * 64;

#pragma unroll
  for (int it = 0; it < 16; ++it) {
    int slot = it * 256 + tid;
    int row = slot >> 6, c16 = slot & 63;
    const float* g = hf + (m0 + row) * 512 + c16 * 8;
    float4v v0 = *(const float4v*)g;
    float4v v1 = *(const float4v*)(g + 4);
    ushort8 u;
    u[0] = f2bf(v0[0]); u[1] = f2bf(v0[1]); u[2] = f2bf(v0[2]); u[3] = f2bf(v0[3]);
    u[4] = f2bf(v1[0]); u[5] = f2bf(v1[1]); u[6] = f2bf(v1[2]); u[7] = f2bf(v1[3]);
    unsigned byte = ((unsigned)(row * 1024 + c16 * 16)) ^ ((unsigned)(row & 7) << 4);
    *(ushort8*)((char*)sH + byte) = u;
  }
  __syncthreads();

  f32x4 acc[4];
  const f32x4 fz = {0.f, 0.f, 0.f, 0.f};
#pragma unroll
  for (int n = 0; n < 4; n++) acc[n] = fz;

  for (int kt = 0; kt < 16; ++kt) {
    int row = w * 16 + l15;
    unsigned byte = ((unsigned)(row * 1024 + kt * 64 + l4 * 16)) ^ ((unsigned)(row & 7) << 4);
    bf16x8 a = ld_bf8_b((const char*)sH, byte);
#pragma unroll
    for (int nt = 0; nt < 4; nt++) {
      bf16x8 b = ld_bf8_g(dwb + (size_t)(nt * 16 + l15) * 512 + kt * 32 + l4 * 8);
      acc[nt] = __builtin_amdgcn_mfma_f32_16x16x32_bf16(a, b, acc[nt], 0, 0, 0);
    }
  }

#pragma unroll
  for (int j = 0; j < 4; j++) {
    size_t r = m0 + w * 16 + l4 * 4 + j;
    float v[4];
    float mx = -1e30f;
#pragma unroll
    for (int nt = 0; nt < 4; nt++) {
      v[nt] = fmaxf(acc[nt][j] + dec_b[nt * 16 + l15], 0.f);
      mx = fmaxf(mx, v[nt]);
    }
#pragma unroll
    for (int msk = 1; msk <= 8; msk <<= 1) mx = fmaxf(mx, __shfl_xor(mx, msk));
    float s = 0.f;
#pragma unroll
    for (int nt = 0; nt < 4; nt++) { v[nt] = __expf(v[nt] - mx); s += v[nt]; }
#pragma unroll
    for (int msk = 1; msk <= 8; msk <<= 1) s += __shfl_xor(s, msk);
    float inv = 1.f / s;
#pragma unroll
    for (int nt = 0; nt < 4; nt++) pi[r * 64 + nt * 16 + l15] = v[nt] * inv;
  }
}

extern "C" void kernel_launch(void* const* d_in, const int* in_sizes, int n_in,
                              void* d_out, int out_size, void* d_ws, size_t ws_size,
                              hipStream_t stream) {
  const float* x     = (const float*)d_in[0];
  const float* h0    = (const float*)d_in[1];
  const float* enc_w = (const float*)d_in[2];
  const float* enc_b = (const float*)d_in[3];
  const float* w_ih  = (const float*)d_in[4];
  const float* w_hh  = (const float*)d_in[5];
  const float* b_ih  = (const float*)d_in[6];
  const float* b_hh  = (const float*)d_in[7];
  const float* dec_w = (const float*)d_in[8];
  const float* dec_b = (const float*)d_in[9];

  float* pi_out = (float*)d_out;
  float* h_out  = (float*)d_out + 4194304;

  unsigned short* ws = (unsigned short*)d_ws;
  size_t off = 0;
  unsigned short* x_bf    = ws + off; off += (size_t)MROWS * VV;
  unsigned short* enc_bf  = ws + off; off += (size_t)MROWS * EE;
  unsigned short* gi_bf   = ws + off; off += (size_t)MROWS * G3;
  unsigned short* encw_bf = ws + off; off += (size_t)EE * VV;
  unsigned short* wih_bf  = ws + off; off += (size_t)G3 * EE;
  unsigned short* whh_bf  = ws + off; off += (size_t)G3 * HH;
  unsigned short* decw_bf = ws + off; off += (size_t)NA * HH;
  unsigned short* hb0     = ws + off; off += (size_t)NSEQ * HH;
  unsigned short* hb1     = ws + off; off += (size_t)NSEQ * HH;
  u32*            cnt32   = (u32*)(ws + off); off += 1024;   // 512 u32
  (void)ws_size; (void)in_sizes; (void)n_in; (void)out_size;

  hipFuncSetAttribute((const void*)gru_scan,
                      hipFuncAttributeMaxDynamicSharedMemorySize, GRU_LDS_BYTES);

  auto cast = [&](const float* s, unsigned short* d, int n) {
    int blocks = (n + 255) / 256; if (blocks > 2048) blocks = 2048;
    cast_f32_bf16<<<blocks, 256, 0, stream>>>(s, d, n);
  };
  cast(x, x_bf, MROWS * VV);
  cast(enc_w, encw_bf, EE * VV);
  cast(w_ih, wih_bf, G3 * EE);
  cast(w_hh, whh_bf, G3 * HH);
  cast(dec_w, decw_bf, NA * HH);
  cast(h0, hb1, NSEQ * HH);              // t=0 reads hbB == hb1

  zero_u32<<<1, 512, 0, stream>>>(cnt32, 512);

  gemm_bt<true><<<(MROWS / 128) * (EE / 128), 256, 0, stream>>>(x_bf, encw_bf, enc_b, enc_bf, EE, VV);
  gemm_bt<false><<<(MROWS / 128) * (G3 / 128), 256, 0, stream>>>(enc_bf, wih_bf, b_ih, gi_bf, G3, EE);

  gru_scan<<<dim3(128), dim3(256), GRU_LDS_BYTES, stream>>>(
      whh_bf, b_hh, gi_bf, h0, hb0, hb1, h_out, cnt32);

  decoder_softmax<<<1024, 256, 0, stream>>>(h_out, decw_bf, dec_b, pi_out);
}